// Round 1
// baseline (1348.026 us; speedup 1.0000x reference)
//
#include <hip/hip_runtime.h>
#include <math.h>

#define N_NODES 8192
#define D_IN    512
#define D_OUT   512
#define N_HEAD  4
#define HC_DIM  2048   // N_HEAD * D_OUT
#define SCALE_QK 0.044194173824159216f  // 1/sqrt(512)

typedef unsigned int  u32;
typedef unsigned short u16;

__device__ __forceinline__ u16 f2bf(float f) {
    u32 u = __float_as_uint(f);
    u32 r = u + 0x7fffu + ((u >> 16) & 1u);   // round-to-nearest-even
    return (u16)(r >> 16);
}
__device__ __forceinline__ void bf8_to_f(uint4 u, float* f) {
    f[0] = __uint_as_float(u.x << 16); f[1] = __uint_as_float(u.x & 0xffff0000u);
    f[2] = __uint_as_float(u.y << 16); f[3] = __uint_as_float(u.y & 0xffff0000u);
    f[4] = __uint_as_float(u.z << 16); f[5] = __uint_as_float(u.z & 0xffff0000u);
    f[6] = __uint_as_float(u.w << 16); f[7] = __uint_as_float(u.w & 0xffff0000u);
}

// ---------------- GEMM1: x @ {Wq,Wk,Wv,Wskip} (M=8192, N=4*2048, K=512) -----
// 64x64 tile, BK=16, 256 threads, 4x4 acc per thread. Q/K/V -> bf16, skip -> f32.
__global__ __launch_bounds__(256) void gemm_qkvs_kernel(
    const float* __restrict__ x,
    const float* __restrict__ Wq, const float* __restrict__ bq,
    const float* __restrict__ Wk, const float* __restrict__ bk,
    const float* __restrict__ Wv, const float* __restrict__ bv,
    const float* __restrict__ Ws, const float* __restrict__ bs,
    u16* __restrict__ Q, u16* __restrict__ K, u16* __restrict__ V,
    float* __restrict__ XATTN)
{
    const int tid = threadIdx.x;
    const int tx = tid & 15, ty = tid >> 4;
    const int m0  = blockIdx.y * 64;
    const int n0g = blockIdx.x * 64;       // global col in [0, 8192)
    const int w   = n0g >> 11;             // which weight matrix
    const int n0  = n0g & 2047;            // local col within that weight

    const float* Wp; const float* bp; u16* Obf = nullptr;
    if (w == 0)      { Wp = Wq; bp = bq; Obf = Q; }
    else if (w == 1) { Wp = Wk; bp = bk; Obf = K; }
    else if (w == 2) { Wp = Wv; bp = bv; Obf = V; }
    else             { Wp = Ws; bp = bs; }

    __shared__ float As[16][64];   // [k][m]
    __shared__ float Bs[16][64];   // [k][n]
    float acc[4][4] = {};

    const int am  = tid >> 2;          // 0..63 row in tile
    const int ak  = (tid & 3) * 4;     // k offset (float4)
    const int bk_ = tid >> 4;          // 0..15 k row
    const int bc  = (tid & 15) * 4;    // col offset (float4)

    const float* aptr = x  + (size_t)(m0 + am) * D_IN + ak;
    const float* bptr = Wp + (size_t)bk_ * HC_DIM + n0 + bc;

    for (int k0 = 0; k0 < D_IN; k0 += 16) {
        float4 av  = *(const float4*)(aptr + k0);
        float4 bv4 = *(const float4*)(bptr + (size_t)k0 * HC_DIM);
        __syncthreads();
        As[ak + 0][am] = av.x; As[ak + 1][am] = av.y;
        As[ak + 2][am] = av.z; As[ak + 3][am] = av.w;
        *(float4*)&Bs[bk_][bc] = bv4;
        __syncthreads();
        #pragma unroll
        for (int kk = 0; kk < 16; kk++) {
            float4 a4 = *(const float4*)&As[kk][ty * 4];
            float4 b4 = *(const float4*)&Bs[kk][tx * 4];
            float ar[4] = {a4.x, a4.y, a4.z, a4.w};
            float br[4] = {b4.x, b4.y, b4.z, b4.w};
            #pragma unroll
            for (int i = 0; i < 4; i++)
                #pragma unroll
                for (int j = 0; j < 4; j++)
                    acc[i][j] += ar[i] * br[j];
        }
    }

    #pragma unroll
    for (int i = 0; i < 4; i++) {
        const int row = m0 + ty * 4 + i;
        #pragma unroll
        for (int j = 0; j < 4; j++) {
            const int col = n0 + tx * 4 + j;
            float val = acc[i][j] + bp[col];
            if (w < 3) Obf[(size_t)row * HC_DIM + col] = f2bf(val);
            else       XATTN[(size_t)row * HC_DIM + col] = val;
        }
    }
}

// ---------------- GEMM2: x_attn @ Wlin + blin + residual -> h ----------------
__global__ __launch_bounds__(256) void gemm_lin_kernel(
    const float* __restrict__ XATTN, const float* __restrict__ Wlin,
    const float* __restrict__ blin, float* __restrict__ Hbuf)
{
    const int tid = threadIdx.x;
    const int tx = tid & 15, ty = tid >> 4;
    const int m0 = blockIdx.y * 64;
    const int n0 = blockIdx.x * 64;    // < 512

    __shared__ float As[16][64];
    __shared__ float Bs[16][64];
    float acc[4][4] = {};

    const int am  = tid >> 2;
    const int ak  = (tid & 3) * 4;
    const int bk_ = tid >> 4;
    const int bc  = (tid & 15) * 4;

    const float* aptr = XATTN + (size_t)(m0 + am) * HC_DIM + ak;
    const float* bptr = Wlin  + (size_t)bk_ * D_OUT + n0 + bc;

    for (int k0 = 0; k0 < HC_DIM; k0 += 16) {
        float4 av  = *(const float4*)(aptr + k0);
        float4 bv4 = *(const float4*)(bptr + (size_t)k0 * D_OUT);
        __syncthreads();
        As[ak + 0][am] = av.x; As[ak + 1][am] = av.y;
        As[ak + 2][am] = av.z; As[ak + 3][am] = av.w;
        *(float4*)&Bs[bk_][bc] = bv4;
        __syncthreads();
        #pragma unroll
        for (int kk = 0; kk < 16; kk++) {
            float4 a4 = *(const float4*)&As[kk][ty * 4];
            float4 b4 = *(const float4*)&Bs[kk][tx * 4];
            float ar[4] = {a4.x, a4.y, a4.z, a4.w};
            float br[4] = {b4.x, b4.y, b4.z, b4.w};
            #pragma unroll
            for (int i = 0; i < 4; i++)
                #pragma unroll
                for (int j = 0; j < 4; j++)
                    acc[i][j] += ar[i] * br[j];
        }
    }

    #pragma unroll
    for (int i = 0; i < 4; i++) {
        const int row = m0 + ty * 4 + i;
        #pragma unroll
        for (int j = 0; j < 4; j++) {
            const int col = n0 + tx * 4 + j;
            float val = acc[i][j] + blin[col] + XATTN[(size_t)row * HC_DIM + col];
            Hbuf[(size_t)row * D_OUT + col] = val;
        }
    }
}

// ---------------- CSR build ----------------
__global__ void zero_kernel(int* __restrict__ p) {
    p[blockIdx.x * 256 + threadIdx.x] = 0;
}
__global__ void hist_kernel(const int* __restrict__ ei, int* __restrict__ counts, int E) {
    const int e = blockIdx.x * 256 + threadIdx.x;
    if (e < E) atomicAdd(&counts[ei[E + e]], 1);
}
__global__ __launch_bounds__(1024) void scan_kernel(
    const int* __restrict__ counts, int* __restrict__ indptr, int* __restrict__ cursor)
{
    __shared__ int sdata[1024];
    const int t = threadIdx.x;
    int local[8]; int sum = 0;
    #pragma unroll
    for (int j = 0; j < 8; j++) { local[j] = counts[t * 8 + j]; sum += local[j]; }
    sdata[t] = sum;
    __syncthreads();
    for (int offd = 1; offd < 1024; offd <<= 1) {
        const int add = (t >= offd) ? sdata[t - offd] : 0;
        __syncthreads();
        sdata[t] += add;
        __syncthreads();
    }
    int run = sdata[t] - sum;   // exclusive base
    #pragma unroll
    for (int j = 0; j < 8; j++) { indptr[t * 8 + j] = run; cursor[t * 8 + j] = run; run += local[j]; }
    if (t == 1023) indptr[N_NODES] = sdata[1023];
}
__global__ void scatter_kernel(const int* __restrict__ ei, int* __restrict__ cursor,
                               int* __restrict__ srcs, int E) {
    const int e = blockIdx.x * 256 + threadIdx.x;
    if (e < E) {
        const int pos = atomicAdd(&cursor[ei[E + e]], 1);
        srcs[pos] = ei[e];
    }
}

// ---------------- per-dst-node attention + aggregation ----------------
// block = 256 threads = 4 waves; wave h handles head h; lane owns 8 channels.
__global__ __launch_bounds__(256) void agg_kernel(
    const u16* __restrict__ Q, const u16* __restrict__ K, const u16* __restrict__ V,
    const int* __restrict__ srcs, const int* __restrict__ indptr,
    float* __restrict__ XATTN)
{
    const int n    = blockIdx.x;
    const int lane = threadIdx.x & 63;
    const int h    = threadIdx.x >> 6;
    const int base = h * D_OUT + lane * 8;

    float qf[8];
    { uint4 u = *(const uint4*)(Q + (size_t)n * HC_DIM + base); bf8_to_f(u, qf); }

    const int beg = indptr[n], end = indptr[n + 1];
    float m = -INFINITY, denom = 0.f;
    float acc[8] = {};
    for (int e = beg; e < end; e++) {
        const int s = srcs[e];
        uint4 ku = *(const uint4*)(K + (size_t)s * HC_DIM + base);
        float kf[8]; bf8_to_f(ku, kf);
        float dot = 0.f;
        #pragma unroll
        for (int j = 0; j < 8; j++) dot += qf[j] * kf[j];
        #pragma unroll
        for (int o = 32; o >= 1; o >>= 1) dot += __shfl_xor(dot, o);
        const float alpha = dot * SCALE_QK;
        const float mn = fmaxf(m, alpha);
        const float scale = __expf(m - mn);     // exp(-inf)=0 handles first edge
        const float p = __expf(alpha - mn);
        uint4 vu = *(const uint4*)(V + (size_t)s * HC_DIM + base);
        float vf[8]; bf8_to_f(vu, vf);
        denom = denom * scale + p;
        #pragma unroll
        for (int j = 0; j < 8; j++) acc[j] = acc[j] * scale + p * vf[j];
        m = mn;
    }
    const float inv = denom > 0.f ? 1.f / denom : 0.f;
    float* xp = XATTN + (size_t)n * HC_DIM + base;
    #pragma unroll
    for (int j = 0; j < 8; j++) xp[j] = acc[j] * inv + xp[j];
}

// ---------------- LayerNorm ----------------
__global__ __launch_bounds__(256) void ln_kernel(
    const float* __restrict__ H, const float* __restrict__ gamma,
    const float* __restrict__ beta, float* __restrict__ out)
{
    const int row = blockIdx.x;
    const int t = threadIdx.x;
    float2 v = *(const float2*)(H + (size_t)row * D_OUT + t * 2);
    float s  = v.x + v.y;
    float ss = v.x * v.x + v.y * v.y;
    #pragma unroll
    for (int o = 32; o >= 1; o >>= 1) { s += __shfl_xor(s, o); ss += __shfl_xor(ss, o); }
    __shared__ float red[8];
    const int wv = t >> 6, lane = t & 63;
    if (lane == 0) { red[wv] = s; red[4 + wv] = ss; }
    __syncthreads();
    s  = red[0] + red[1] + red[2] + red[3];
    ss = red[4] + red[5] + red[6] + red[7];
    const float mu  = s * (1.f / D_OUT);
    const float var = ss * (1.f / D_OUT) - mu * mu;
    const float inv = rsqrtf(var + 1e-5f);
    const int c = t * 2;
    float2 g  = *(const float2*)(gamma + c);
    float2 bb = *(const float2*)(beta + c);
    float2 o2;
    o2.x = g.x * (v.x - mu) * inv + bb.x;
    o2.y = g.y * (v.y - mu) * inv + bb.y;
    *(float2*)(out + (size_t)row * D_OUT + c) = o2;
}

extern "C" void kernel_launch(void* const* d_in, const int* in_sizes, int n_in,
                              void* d_out, int out_size, void* d_ws, size_t ws_size,
                              hipStream_t stream)
{
    const float* x    = (const float*)d_in[0];
    const int*   ei   = (const int*)d_in[1];
    const float* Wq   = (const float*)d_in[2];
    const float* bq   = (const float*)d_in[3];
    const float* Wk   = (const float*)d_in[4];
    const float* bk   = (const float*)d_in[5];
    const float* Wv   = (const float*)d_in[6];
    const float* bv   = (const float*)d_in[7];
    const float* Ws   = (const float*)d_in[8];
    const float* bs   = (const float*)d_in[9];
    const float* Wlin = (const float*)d_in[10];
    const float* blin = (const float*)d_in[11];
    const float* gamma= (const float*)d_in[12];
    const float* beta = (const float*)d_in[13];
    float* out = (float*)d_out;
    const int E = in_sizes[1] / 2;

    char* ws = (char*)d_ws;
    size_t off = 0;
    auto alloc = [&](size_t bytes) -> char* {
        char* p = ws + off; off += (bytes + 255) & ~(size_t)255; return p;
    };
    u16*  Q      = (u16*)alloc((size_t)N_NODES * HC_DIM * 2);
    u16*  Kb     = (u16*)alloc((size_t)N_NODES * HC_DIM * 2);
    u16*  Vb     = (u16*)alloc((size_t)N_NODES * HC_DIM * 2);
    float* XATTN = (float*)alloc((size_t)N_NODES * HC_DIM * 4);
    float* Hbuf  = (float*)alloc((size_t)N_NODES * D_OUT * 4);
    int*  counts = (int*)alloc(N_NODES * 4);
    int*  cursor = (int*)alloc(N_NODES * 4);
    int*  indptr = (int*)alloc((N_NODES + 1) * 4);
    int*  srcs   = (int*)alloc((size_t)E * 4);

    gemm_qkvs_kernel<<<dim3(HC_DIM * 4 / 64, N_NODES / 64), 256, 0, stream>>>(
        x, Wq, bq, Wk, bk, Wv, bv, Ws, bs, Q, Kb, Vb, XATTN);
    zero_kernel<<<N_NODES / 256, 256, 0, stream>>>(counts);
    hist_kernel<<<(E + 255) / 256, 256, 0, stream>>>(ei, counts, E);
    scan_kernel<<<1, 1024, 0, stream>>>(counts, indptr, cursor);
    scatter_kernel<<<(E + 255) / 256, 256, 0, stream>>>(ei, cursor, srcs, E);
    agg_kernel<<<N_NODES, 256, 0, stream>>>(Q, Kb, Vb, srcs, indptr, XATTN);
    gemm_lin_kernel<<<dim3(D_OUT / 64, N_NODES / 64), 256, 0, stream>>>(
        XATTN, Wlin, blin, Hbuf);
    ln_kernel<<<N_NODES, 256, 0, stream>>>(Hbuf, gamma, beta, out);
}

// Round 2
// 333.193 us; speedup vs baseline: 4.0458x; 4.0458x over previous
//
#include <hip/hip_runtime.h>
#include <math.h>

#define N_NODES 8192
#define D_IN    512
#define D_OUT   512
#define HC_DIM  2048   // 4 heads * 512
#define SCALE_QK 0.044194173824159216f  // 1/sqrt(512)

typedef unsigned int  u32;
typedef unsigned short u16;
typedef __bf16 bf16;
typedef __attribute__((ext_vector_type(8))) __bf16 bf16x8;
typedef __attribute__((ext_vector_type(4))) float  floatx4;

__device__ __forceinline__ u16 f2bf(float f) {
    u32 u = __float_as_uint(f);
    u32 r = u + 0x7fffu + ((u >> 16) & 1u);   // round-to-nearest-even
    return (u16)(r >> 16);
}
__device__ __forceinline__ void bf8_to_f(uint4 u, float* f) {
    f[0] = __uint_as_float(u.x << 16); f[1] = __uint_as_float(u.x & 0xffff0000u);
    f[2] = __uint_as_float(u.y << 16); f[3] = __uint_as_float(u.y & 0xffff0000u);
    f[4] = __uint_as_float(u.z << 16); f[5] = __uint_as_float(u.z & 0xffff0000u);
    f[6] = __uint_as_float(u.w << 16); f[7] = __uint_as_float(u.w & 0xffff0000u);
}
__device__ __forceinline__ void glds16(const void* g, void* l) {
    __builtin_amdgcn_global_load_lds(
        (__attribute__((address_space(1))) void*)(g),
        (__attribute__((address_space(3))) void*)(l), 16, 0, 0);
}

// ---------------- fp32 -> bf16 straight copy (x) ----------------
__global__ __launch_bounds__(256) void f2bf_kernel(
    const float* __restrict__ src, u16* __restrict__ dst)
{
    const size_t i = ((size_t)blockIdx.x * 256 + threadIdx.x) * 8;
    float4 a = *(const float4*)(src + i);
    float4 b = *(const float4*)(src + i + 4);
    uint4 o;
    o.x = f2bf(a.x) | ((u32)f2bf(a.y) << 16);
    o.y = f2bf(a.z) | ((u32)f2bf(a.w) << 16);
    o.z = f2bf(b.x) | ((u32)f2bf(b.y) << 16);
    o.w = f2bf(b.z) | ((u32)f2bf(b.w) << 16);
    *(uint4*)(dst + i) = o;
}

// ------------- fp32 [R][C] -> bf16 dst[C][R] (transpose) -------------
__global__ __launch_bounds__(256) void transpose_f2bf_kernel(
    const float* __restrict__ src, u16* __restrict__ dst,
    int R, int C, int dst_ld)
{
    __shared__ float t[32][33];
    const int c0 = blockIdx.x * 32, r0 = blockIdx.y * 32;
    const int tr = threadIdx.x >> 3;         // 0..31
    const int tc = (threadIdx.x & 7) * 4;    // 0..28
    float4 v = *(const float4*)(src + (size_t)(r0 + tr) * C + c0 + tc);
    t[tr][tc] = v.x; t[tr][tc + 1] = v.y; t[tr][tc + 2] = v.z; t[tr][tc + 3] = v.w;
    __syncthreads();
    ushort4 ov;
    ov.x = f2bf(t[tc + 0][tr]); ov.y = f2bf(t[tc + 1][tr]);
    ov.z = f2bf(t[tc + 2][tr]); ov.w = f2bf(t[tc + 3][tr]);
    *(ushort4*)(dst + (size_t)(c0 + tr) * dst_ld + r0 + tc) = ov;
}

// ---------------- GEMM1 (MFMA): xb[8192,512] @ W^T -> Q/K/V/skip ----------------
// 128x128 tile, BK=32, 256 thr = 4 waves, wave tile 64x64 (4x4 frags of 16x16x32).
__global__ __launch_bounds__(256) void gemm1_mfma(
    const bf16* __restrict__ xb, const bf16* __restrict__ Wt,
    const float* __restrict__ bq, const float* __restrict__ bk2,
    const float* __restrict__ bv2, const float* __restrict__ bs,
    u16* __restrict__ Qo, u16* __restrict__ Ko, u16* __restrict__ Vo,
    u16* __restrict__ XBo)
{
    __shared__ __align__(16) bf16 As[128 * 32];
    __shared__ __align__(16) bf16 Bs[128 * 32];
    const int tid = threadIdx.x;
    const int lane = tid & 63, wave = tid >> 6;
    const int wm = wave >> 1, wn = wave & 1;
    const int m0  = blockIdx.y * 128;
    const int n0g = blockIdx.x * 128;

    const bf16* a0 = xb + (size_t)(m0  + (tid >> 2)) * D_IN + (tid & 3) * 8;
    const bf16* b0 = Wt + (size_t)(n0g + (tid >> 2)) * D_IN + (tid & 3) * 8;

    floatx4 acc[4][4] = {};

    for (int k0 = 0; k0 < D_IN; k0 += 32) {
        __syncthreads();
        glds16(a0 + k0,              &As[tid * 8]);
        glds16(a0 + 64 * D_IN + k0,  &As[2048 + tid * 8]);
        glds16(b0 + k0,              &Bs[tid * 8]);
        glds16(b0 + 64 * D_IN + k0,  &Bs[2048 + tid * 8]);
        __syncthreads();
        bf16x8 af[4], bfr[4];
        #pragma unroll
        for (int i = 0; i < 4; i++) {
            af[i]  = *(const bf16x8*)&As[(wm * 64 + i * 16 + (lane & 15)) * 32 + (lane >> 4) * 8];
            bfr[i] = *(const bf16x8*)&Bs[(wn * 64 + i * 16 + (lane & 15)) * 32 + (lane >> 4) * 8];
        }
        #pragma unroll
        for (int i = 0; i < 4; i++)
            #pragma unroll
            for (int j = 0; j < 4; j++)
                acc[i][j] = __builtin_amdgcn_mfma_f32_16x16x32_bf16(af[i], bfr[j], acc[i][j], 0, 0, 0);
    }

    const int w  = n0g >> 11;
    const int n0 = n0g & 2047;
    const float* bias = (w == 0) ? bq : (w == 1) ? bk2 : (w == 2) ? bv2 : bs;
    u16* dst = (w == 0) ? Qo : (w == 1) ? Ko : (w == 2) ? Vo : XBo;

    #pragma unroll
    for (int i = 0; i < 4; i++) {
        const int row = m0 + wm * 64 + i * 16 + ((lane >> 4) << 2);
        #pragma unroll
        for (int j = 0; j < 4; j++) {
            const int col = n0 + wn * 64 + j * 16 + (lane & 15);
            const float bb = bias[col];
            #pragma unroll
            for (int r = 0; r < 4; r++)
                dst[(size_t)(row + r) * HC_DIM + col] = f2bf(acc[i][j][r] + bb);
        }
    }
}

// ---------------- GEMM2 (MFMA): XB[8192,2048] @ Wlin^T + blin + residual ----------------
// 64x128 tile, BK=32, 4 waves, wave tile 32x64 (2x4 frags).
__global__ __launch_bounds__(256) void gemm2_mfma(
    const u16* __restrict__ XB, const bf16* __restrict__ Wlt,
    const float* __restrict__ blin, float* __restrict__ Hb)
{
    __shared__ __align__(16) bf16 As[64 * 32];
    __shared__ __align__(16) bf16 Bs[128 * 32];
    const int tid = threadIdx.x;
    const int lane = tid & 63, wave = tid >> 6;
    const int wm = wave >> 1, wn = wave & 1;
    const int m0 = blockIdx.y * 64;
    const int n0 = blockIdx.x * 128;

    const bf16* a0 = (const bf16*)XB + (size_t)(m0 + (tid >> 2)) * HC_DIM + (tid & 3) * 8;
    const bf16* b0 = Wlt + (size_t)(n0 + (tid >> 2)) * HC_DIM + (tid & 3) * 8;

    floatx4 acc[2][4] = {};

    for (int k0 = 0; k0 < HC_DIM; k0 += 32) {
        __syncthreads();
        glds16(a0 + k0,               &As[tid * 8]);
        glds16(b0 + k0,               &Bs[tid * 8]);
        glds16(b0 + 64 * HC_DIM + k0, &Bs[2048 + tid * 8]);
        __syncthreads();
        bf16x8 af[2], bfr[4];
        #pragma unroll
        for (int i = 0; i < 2; i++)
            af[i] = *(const bf16x8*)&As[(wm * 32 + i * 16 + (lane & 15)) * 32 + (lane >> 4) * 8];
        #pragma unroll
        for (int j = 0; j < 4; j++)
            bfr[j] = *(const bf16x8*)&Bs[(wn * 64 + j * 16 + (lane & 15)) * 32 + (lane >> 4) * 8];
        #pragma unroll
        for (int i = 0; i < 2; i++)
            #pragma unroll
            for (int j = 0; j < 4; j++)
                acc[i][j] = __builtin_amdgcn_mfma_f32_16x16x32_bf16(af[i], bfr[j], acc[i][j], 0, 0, 0);
    }

    #pragma unroll
    for (int i = 0; i < 2; i++) {
        const int row = m0 + wm * 32 + i * 16 + ((lane >> 4) << 2);
        #pragma unroll
        for (int j = 0; j < 4; j++) {
            const int col = n0 + wn * 64 + j * 16 + (lane & 15);
            const float bb = blin[col];
            #pragma unroll
            for (int r = 0; r < 4; r++) {
                const int rr = row + r;
                const float res = __uint_as_float((u32)XB[(size_t)rr * HC_DIM + col] << 16);
                Hb[(size_t)rr * D_OUT + col] = acc[i][j][r] + bb + res;
            }
        }
    }
}

// ---------------- CSR build ----------------
__global__ void zero_kernel(int* __restrict__ p) {
    p[blockIdx.x * 256 + threadIdx.x] = 0;
}
__global__ void hist_kernel(const int* __restrict__ ei, int* __restrict__ counts, int E) {
    const int e = blockIdx.x * 256 + threadIdx.x;
    if (e < E) atomicAdd(&counts[ei[E + e]], 1);
}
__global__ __launch_bounds__(1024) void scan_kernel(
    const int* __restrict__ counts, int* __restrict__ indptr, int* __restrict__ cursor)
{
    __shared__ int sdata[1024];
    const int t = threadIdx.x;
    int local[8]; int sum = 0;
    #pragma unroll
    for (int j = 0; j < 8; j++) { local[j] = counts[t * 8 + j]; sum += local[j]; }
    sdata[t] = sum;
    __syncthreads();
    for (int offd = 1; offd < 1024; offd <<= 1) {
        const int add = (t >= offd) ? sdata[t - offd] : 0;
        __syncthreads();
        sdata[t] += add;
        __syncthreads();
    }
    int run = sdata[t] - sum;
    #pragma unroll
    for (int j = 0; j < 8; j++) { indptr[t * 8 + j] = run; cursor[t * 8 + j] = run; run += local[j]; }
    if (t == 1023) indptr[N_NODES] = sdata[1023];
}
__global__ void scatter_kernel(const int* __restrict__ ei, int* __restrict__ cursor,
                               int* __restrict__ srcs, int E) {
    const int e = blockIdx.x * 256 + threadIdx.x;
    if (e < E) {
        const int pos = atomicAdd(&cursor[ei[E + e]], 1);
        srcs[pos] = ei[e];
    }
}

// ---------------- per-dst-node attention + aggregation ----------------
// block = 256 threads = 4 waves; wave h handles head h; lane owns 8 channels.
// Reads skip (bf16) from XB, writes x_attn (bf16) back to XB.
__global__ __launch_bounds__(256) void agg_kernel(
    const u16* __restrict__ Q, const u16* __restrict__ K, const u16* __restrict__ V,
    const int* __restrict__ srcs, const int* __restrict__ indptr,
    u16* __restrict__ XB)
{
    const int n    = blockIdx.x;
    const int lane = threadIdx.x & 63;
    const int h    = threadIdx.x >> 6;
    const int base = h * D_OUT + lane * 8;

    float qf[8];
    { uint4 u = *(const uint4*)(Q + (size_t)n * HC_DIM + base); bf8_to_f(u, qf); }

    const int beg = indptr[n], end = indptr[n + 1];
    float m = -INFINITY, denom = 0.f;
    float acc[8] = {};
    for (int e = beg; e < end; e++) {
        const int s = srcs[e];
        uint4 ku = *(const uint4*)(K + (size_t)s * HC_DIM + base);
        float kf[8]; bf8_to_f(ku, kf);
        float dot = 0.f;
        #pragma unroll
        for (int j = 0; j < 8; j++) dot += qf[j] * kf[j];
        #pragma unroll
        for (int o = 32; o >= 1; o >>= 1) dot += __shfl_xor(dot, o);
        const float alpha = dot * SCALE_QK;
        const float mn = fmaxf(m, alpha);
        const float scale = __expf(m - mn);
        const float p = __expf(alpha - mn);
        uint4 vu = *(const uint4*)(V + (size_t)s * HC_DIM + base);
        float vf[8]; bf8_to_f(vu, vf);
        denom = denom * scale + p;
        #pragma unroll
        for (int j = 0; j < 8; j++) acc[j] = acc[j] * scale + p * vf[j];
        m = mn;
    }
    const float inv = denom > 0.f ? 1.f / denom : 0.f;
    u16* xp = XB + (size_t)n * HC_DIM + base;
    uint4 su = *(const uint4*)xp;
    float sf[8]; bf8_to_f(su, sf);
    float o[8];
    #pragma unroll
    for (int j = 0; j < 8; j++) o[j] = acc[j] * inv + sf[j];
    uint4 ou;
    ou.x = f2bf(o[0]) | ((u32)f2bf(o[1]) << 16);
    ou.y = f2bf(o[2]) | ((u32)f2bf(o[3]) << 16);
    ou.z = f2bf(o[4]) | ((u32)f2bf(o[5]) << 16);
    ou.w = f2bf(o[6]) | ((u32)f2bf(o[7]) << 16);
    *(uint4*)xp = ou;
}

// ---------------- LayerNorm ----------------
__global__ __launch_bounds__(256) void ln_kernel(
    const float* __restrict__ H, const float* __restrict__ gamma,
    const float* __restrict__ beta, float* __restrict__ out)
{
    const int row = blockIdx.x;
    const int t = threadIdx.x;
    float2 v = *(const float2*)(H + (size_t)row * D_OUT + t * 2);
    float s  = v.x + v.y;
    float ss = v.x * v.x + v.y * v.y;
    #pragma unroll
    for (int o = 32; o >= 1; o >>= 1) { s += __shfl_xor(s, o); ss += __shfl_xor(ss, o); }
    __shared__ float red[8];
    const int wv = t >> 6, lane = t & 63;
    if (lane == 0) { red[wv] = s; red[4 + wv] = ss; }
    __syncthreads();
    s  = red[0] + red[1] + red[2] + red[3];
    ss = red[4] + red[5] + red[6] + red[7];
    const float mu  = s * (1.f / D_OUT);
    const float var = ss * (1.f / D_OUT) - mu * mu;
    const float inv = rsqrtf(var + 1e-5f);
    const int c = t * 2;
    float2 g  = *(const float2*)(gamma + c);
    float2 bb = *(const float2*)(beta + c);
    float2 o2;
    o2.x = g.x * (v.x - mu) * inv + bb.x;
    o2.y = g.y * (v.y - mu) * inv + bb.y;
    *(float2*)(out + (size_t)row * D_OUT + c) = o2;
}

extern "C" void kernel_launch(void* const* d_in, const int* in_sizes, int n_in,
                              void* d_out, int out_size, void* d_ws, size_t ws_size,
                              hipStream_t stream)
{
    const float* x    = (const float*)d_in[0];
    const int*   ei   = (const int*)d_in[1];
    const float* Wq   = (const float*)d_in[2];
    const float* bq   = (const float*)d_in[3];
    const float* Wk   = (const float*)d_in[4];
    const float* bk   = (const float*)d_in[5];
    const float* Wv   = (const float*)d_in[6];
    const float* bv   = (const float*)d_in[7];
    const float* Ws   = (const float*)d_in[8];
    const float* bs   = (const float*)d_in[9];
    const float* Wlin = (const float*)d_in[10];
    const float* blin = (const float*)d_in[11];
    const float* gamma= (const float*)d_in[12];
    const float* beta = (const float*)d_in[13];
    float* out = (float*)d_out;
    const int E = in_sizes[1] / 2;

    char* ws = (char*)d_ws;
    size_t off = 0;
    auto alloc = [&](size_t bytes) -> char* {
        char* p = ws + off; off += (bytes + 255) & ~(size_t)255; return p;
    };
    u16* xb   = (u16*)alloc((size_t)N_NODES * D_IN * 2);
    u16* Wt   = (u16*)alloc((size_t)4 * HC_DIM * D_IN * 2);   // [8192 n][512 k]
    u16* Wlt  = (u16*)alloc((size_t)D_OUT * HC_DIM * 2);      // [512 n][2048 k]
    u16* Q    = (u16*)alloc((size_t)N_NODES * HC_DIM * 2);
    u16* Kb   = (u16*)alloc((size_t)N_NODES * HC_DIM * 2);
    u16* Vb   = (u16*)alloc((size_t)N_NODES * HC_DIM * 2);
    u16* XB   = (u16*)alloc((size_t)N_NODES * HC_DIM * 2);
    int* counts = (int*)alloc(N_NODES * 4);
    int* cursor = (int*)alloc(N_NODES * 4);
    int* indptr = (int*)alloc((N_NODES + 1) * 4);
    int* srcs   = (int*)alloc((size_t)E * 4);
    float* Hbuf = (float*)Q;   // alias: Q is dead after agg_kernel

    // conversions
    f2bf_kernel<<<(N_NODES * D_IN) / (256 * 8), 256, 0, stream>>>(x, xb);
    transpose_f2bf_kernel<<<dim3(HC_DIM / 32, D_IN / 32), 256, 0, stream>>>(
        Wq, Wt + (size_t)0 * HC_DIM * D_IN, D_IN, HC_DIM, D_IN);
    transpose_f2bf_kernel<<<dim3(HC_DIM / 32, D_IN / 32), 256, 0, stream>>>(
        Wk, Wt + (size_t)1 * HC_DIM * D_IN, D_IN, HC_DIM, D_IN);
    transpose_f2bf_kernel<<<dim3(HC_DIM / 32, D_IN / 32), 256, 0, stream>>>(
        Wv, Wt + (size_t)2 * HC_DIM * D_IN, D_IN, HC_DIM, D_IN);
    transpose_f2bf_kernel<<<dim3(HC_DIM / 32, D_IN / 32), 256, 0, stream>>>(
        Ws, Wt + (size_t)3 * HC_DIM * D_IN, D_IN, HC_DIM, D_IN);
    transpose_f2bf_kernel<<<dim3(D_OUT / 32, HC_DIM / 32), 256, 0, stream>>>(
        Wlin, Wlt, HC_DIM, D_OUT, HC_DIM);

    // GEMM1: Q/K/V/skip
    gemm1_mfma<<<dim3(4 * HC_DIM / 128, N_NODES / 128), 256, 0, stream>>>(
        (const bf16*)xb, (const bf16*)Wt, bq, bk, bv, bs, Q, Kb, Vb, XB);

    // CSR
    zero_kernel<<<N_NODES / 256, 256, 0, stream>>>(counts);
    hist_kernel<<<(E + 255) / 256, 256, 0, stream>>>(ei, counts, E);
    scan_kernel<<<1, 1024, 0, stream>>>(counts, indptr, cursor);
    scatter_kernel<<<(E + 255) / 256, 256, 0, stream>>>(ei, cursor, srcs, E);

    // attention aggregate (+skip) -> XB (bf16)
    agg_kernel<<<N_NODES, 256, 0, stream>>>(Q, Kb, Vb, srcs, indptr, XB);

    // GEMM2 + residual -> Hbuf
    gemm2_mfma<<<dim3(D_OUT / 128, N_NODES / 64), 256, 0, stream>>>(
        XB, (const bf16*)Wlt, blin, Hbuf);

    // LayerNorm
    ln_kernel<<<N_NODES, 256, 0, stream>>>(Hbuf, gamma, beta, out);
}